// Round 6
// baseline (1268.961 us; speedup 1.0000x reference)
//
#include <hip/hip_runtime.h>
#include <hip/hip_fp16.h>

typedef unsigned int u32;

// Soft-DTW fwd, T=4096, D=16, gamma=1. fp32 log2-domain DP (R' = R*log2e):
// R'[i,j] = d' + m - log2(1 + 2^(m-md) + 2^(m-M)) over (up, diag, left).
// 16 blocks x 4 waves x 64 lanes, 1 row/lane, 1 wave/SIMD (issue-bound
// optimum: ~47 VALU-cyc/step/wave). Skewed wavefront: lane l at local step s
// computes column j = s - l; intra-wave row handoff via DPP wave_shr1.
// Wave-to-wave handoff: FULL-ROW rings (written once, no wrap -> no
// re-sentinel, no backpressure, deadlock-free): 48 hops via 50 KB LDS rings,
// 15 hops via global sentinel rings (relaxed agent atomics). 2-phase modulo
// register prefetch (16 steps deep, no rotation copies -> no waitcnt drain).

constexpr int   kN      = 4096;
constexpr int   kLanes  = 64;
constexpr int   kWaves  = 4;               // per block (1 per SIMD)
constexpr int   kBlocks = 16;
constexpr int   kSMax   = kN + kLanes;     // 4160 local steps
constexpr int   kG      = 8;               // steps per group
constexpr int   kGroups = kSMax / kG;      // 520
constexpr u32   kSent   = 0xFFFFFFFFu;     // NaN pattern, never a real value
constexpr float kBig    = 1e10f;
constexpr float kLog2e  = 1.4426950408889634f;
constexpr float kLn2    = 0.6931471805599453f;
constexpr int   kGRS    = kSMax + 64;      // global ring stride (u32) = 4224
constexpr int   kGRTot  = (kBlocks - 1) * kGRS;
constexpr int   kLRS    = kSMax + 8;       // LDS ring stride = 4168 (full row)
constexpr int   kLdsTot = (kWaves - 1) * kLRS;   // 12504 u32 = 50 KB

#if __has_builtin(__builtin_amdgcn_exp2f)
#define EXP2F(x) __builtin_amdgcn_exp2f(x)
#else
#define EXP2F(x) exp2f(x)
#endif
#if __has_builtin(__builtin_amdgcn_logf)
#define LOG2F(x) __builtin_amdgcn_logf(x)
#else
#define LOG2F(x) log2f(x)
#endif

__device__ __forceinline__ float med3f(float a, float b, float c) {
#if __has_builtin(__builtin_amdgcn_fmed3f)
  return __builtin_amdgcn_fmed3f(a, b, c);
#else
  return fmaxf(fminf(a, b), fminf(fmaxf(a, b), c));
#endif
}

__device__ __forceinline__ float dppShr1f(float v) {
  // wave_shr1: lane l <- lane l-1 (full-wave); lane 0 old(=0), cndmask'd at use
  return __int_as_float(__builtin_amdgcn_update_dpp(0, __float_as_int(v), 0x138, 0xF, 0xF, false));
}

__device__ __forceinline__ u32 aloadG(const u32* p) {
  return __hip_atomic_load(p, __ATOMIC_RELAXED, __HIP_MEMORY_SCOPE_AGENT);
}
__device__ __forceinline__ void astoreG(u32* p, u32 v) {
  __hip_atomic_store(p, v, __ATOMIC_RELAXED, __HIP_MEMORY_SCOPE_AGENT);
}
__device__ __forceinline__ u32 aloadL(const u32* p) {
  return __hip_atomic_load(p, __ATOMIC_RELAXED, __HIP_MEMORY_SCOPE_WORKGROUP);
}
__device__ __forceinline__ void astoreL(u32* p, u32 v) {
  __hip_atomic_store(p, v, __ATOMIC_RELAXED, __HIP_MEMORY_SCOPE_WORKGROUP);
}

__device__ __forceinline__ float cell2(float u, float g, float p, float dpv) {
  const float m  = fminf(fminf(u, g), p);
  const float M  = fmaxf(fmaxf(u, g), p);
  const float md = med3f(u, g, p);
  const float e1 = EXP2F(m - md);
  const float e2 = EXP2F(m - M);
  const float lg = LOG2F(1.0f + e1 + e2);
  return (dpv + m) - lg;
}

__global__ __launch_bounds__(256) void sdtw_prep(const float* __restrict__ A,
                                                 const float* __restrict__ B,
                                                 uint4* __restrict__ Et,
                                                 u32* __restrict__ gring) {
  const int tid = threadIdx.x;
  const int w   = blockIdx.y;                         // band 0..63
  const int gid = ((w * (int)gridDim.x + (int)blockIdx.x) << 8) + tid;
  if (gid < kGRTot) gring[gid] = kSent;

  const int l   = tid & 63;
  const int grp = (int)blockIdx.x * 4 + (tid >> 6);

  const float4* Ap = (const float4*)(A + (size_t)(w * 64 + l) * 16);
  const float4 a0 = Ap[0], a1 = Ap[1], a2 = Ap[2], a3 = Ap[3];
  auto sq = [](float4 a, float4 b) {
    const float dx = a.x - b.x, dy = a.y - b.y, dz = a.z - b.z, dw = a.w - b.w;
    return fmaf(dx, dx, fmaf(dy, dy, fmaf(dz, dz, dw * dw)));
  };
  u32 hp[4];
#pragma unroll
  for (int pr = 0; pr < 4; ++pr) {
    float dv[2];
#pragma unroll
    for (int h = 0; h < 2; ++h) {
      const int q = pr * 2 + h;
      const int s = grp * kG + q + 1;
      const int jb = min(max(s - l - 1, 0), kN - 1);
      const float4* Bp = (const float4*)(B + (size_t)jb * 16);
      dv[h] = (sq(a0, Bp[0]) + sq(a1, Bp[1]) + sq(a2, Bp[2]) + sq(a3, Bp[3])) * kLog2e;
    }
    hp[pr] = ((u32)__half_as_ushort(__float2half(dv[1])) << 16)
           |  (u32)__half_as_ushort(__float2half(dv[0]));
  }
  Et[((size_t)w * kGroups + grp) * 64 + l] = make_uint4(hp[0], hp[1], hp[2], hp[3]);
}

template <bool MASK>
__device__ __forceinline__ void run2(
    int gBeg, int gEnd, int l, int v, int b,
    const uint4* __restrict__ EtL,
    const u32* __restrict__ gin, u32* __restrict__ gout,
    const u32* __restrict__ lin, u32* __restrict__ lout,
    float& p, float& dm, u32 (&c)[2][kG], uint4 (&e2)[2],
    float* __restrict__ out) {
  const bool consG    = (v == 0) && (b > 0);
  const bool consNone = (v == 0) && (b == 0);
  const bool consL    = (v > 0);
  const bool prodL    = (v < kWaves - 1);
  const bool prodG    = (v == kWaves - 1) && (b < kBlocks - 1);
  const bool isL0  = (l == 0);
  const bool isL63 = (l == kLanes - 1);

  for (int g2 = gBeg; g2 < gEnd; g2 += 2) {
#pragma unroll
    for (int ph = 0; ph < 2; ++ph) {
      const int g = g2 + ph;

      // ---- verify group g's poll entries (wave-uniform; rare slow path) ----
      if (!consNone) {
        u32 mm = c[ph][0];
#pragma unroll
        for (int q = 1; q < kG; ++q) mm = mm > c[ph][q] ? mm : c[ph][q];
        if (mm == kSent) {
#pragma unroll
          for (int q = 0; q < kG; ++q) {
            const int e = g * kG + q;
            if (!MASK || e < kN) {
              u32 vv = c[ph][q];
              if (consG) { while (vv == kSent) vv = aloadG(gin + e); }
              else       { while (vv == kSent) vv = aloadL(lin + e); }
              c[ph][q] = vv;
            }
          }
        }
      }

      // ---- 8 cells ----
      const u32 ecs[4] = {e2[ph].x, e2[ph].y, e2[ph].z, e2[ph].w};
#pragma unroll
      for (int q = 0; q < kG; ++q) {
        const int s = g * kG + q + 1;
        float um = dppShr1f(p);
        const float inj = consNone ? kBig : __uint_as_float(c[ph][q]);
        um = isL0 ? inj : um;
        u32 hw = ecs[q >> 1];
        if (q & 1) hw >>= 16;
        const float dpv = __half2float(__ushort_as_half((unsigned short)(hw & 0xFFFFu)));
        float r = cell2(um, dm, p, dpv);
        if (MASK) { const int j = s - l; r = (j >= 1 && j <= kN) ? r : kBig; }
        dm = um; p = r;

        if (prodL) {
          if (isL63) {
            int e = s - kLanes;                     // entry = column - 1
            if (MASK) { const bool ok = (e >= 0) && (e < kN); e = ok ? e : kSMax; }
            astoreL(const_cast<u32*>(lout) + e, __float_as_uint(r));
          }
        } else if (prodG) {
          if (isL63) {
            int e = s - kLanes;
            if (MASK) { const bool ok = (e >= 0) && (e < kN); e = ok ? e : kSMax; }
            astoreG(gout + e, __float_as_uint(r));
          }
        } else if (MASK) {
          if (isL63 && s == kN + kLanes - 1) out[0] = r * kLn2;   // R[4096,4096]
        }
      }

      // ---- prefetch this phase for group g+2 (16-step slack, no copies) ----
      {
        const int gl = g + 2;
        const int gc = gl < kGroups ? gl : kGroups - 1;
        e2[ph] = EtL[(size_t)gc * 64];
        const int eb = min(gl * kG, kSMax);         // stays in-ring
        if (consG) {
#pragma unroll
          for (int q = 0; q < kG; ++q) c[ph][q] = aloadG(gin + eb + q);
        } else if (consL) {
          const uint4* lp = (const uint4*)(lin + eb);
          const uint4 t0 = lp[0], t1 = lp[1];
          c[ph][0] = t0.x; c[ph][1] = t0.y; c[ph][2] = t0.z; c[ph][3] = t0.w;
          c[ph][4] = t1.x; c[ph][5] = t1.y; c[ph][6] = t1.z; c[ph][7] = t1.w;
        }
      }
    }
  }
}

__global__ __launch_bounds__(kWaves * kLanes) void sdtw_dp(const uint4* __restrict__ Et,
                                                           u32* __restrict__ gring,
                                                           float* __restrict__ out) {
  const int tid = threadIdx.x;
  const int v = tid >> 6, l = tid & 63;
  const int b = blockIdx.x;
  const int W = b * kWaves + v;                 // band 0..63 (row = 64W + l + 1)

  __shared__ u32 ring[kLdsTot];
  for (int i = tid; i < kLdsTot; i += kWaves * kLanes) ring[i] = kSent;
  __syncthreads();

  const uint4* EtL = Et + (size_t)W * kGroups * 64 + l;
  const u32* gin = gring + (size_t)(b > 0 ? b - 1 : 0) * kGRS;
  u32* gout = gring + (size_t)(b < kBlocks - 1 ? b : 0) * kGRS;
  const u32* lin = ring + (v > 0 ? v - 1 : 0) * kLRS;
  u32* lout = ring + (v < kWaves - 1 ? v : 0) * kLRS;

  float p  = kBig;                               // R'[row, 0] left boundary
  float dm = (W == 0 && l == 0) ? 0.0f : kBig;   // R'[row-1, 0]; R'[0,0] = 0

  const bool consG = (v == 0) && (b > 0);
  const bool consL = (v > 0);
  u32 c[2][kG];
  uint4 e2[2];
#pragma unroll
  for (int ph = 0; ph < 2; ++ph) {
    e2[ph] = EtL[(size_t)ph * 64];
#pragma unroll
    for (int q = 0; q < kG; ++q) {
      const int e = ph * kG + q;
      u32 val = __float_as_uint(kBig);
      if (consG)      val = aloadG(gin + e);
      else if (consL) val = aloadL(lin + e);
      c[ph][q] = val;
    }
  }

  run2<true >(0,   8,       l, v, b, EtL, gin, gout, lin, lout, p, dm, c, e2, out);
  run2<false>(8,   512,     l, v, b, EtL, gin, gout, lin, lout, p, dm, c, e2, out);
  run2<true >(512, kGroups, l, v, b, EtL, gin, gout, lin, lout, p, dm, c, e2, out);
}

extern "C" void kernel_launch(void* const* d_in, const int* in_sizes, int n_in,
                              void* d_out, int out_size, void* d_ws, size_t ws_size,
                              hipStream_t stream) {
  const float* A = (const float*)d_in[0];
  const float* B = (const float*)d_in[1];
  float* out = (float*)d_out;

  u32* gring = (u32*)d_ws;
  uint4* Et = (uint4*)(gring + kGRTot);
  // ws need: 15*4224*4 B + 64*520*64*16 B ~= 0.25 MB + 34.1 MB (fits, per R2)

  sdtw_prep<<<dim3(kGroups / 4, 64), 256, 0, stream>>>(A, B, Et, gring);
  sdtw_dp<<<kBlocks, kWaves * kLanes, 0, stream>>>(Et, gring, out);
}